// Round 1
// baseline (784.887 us; speedup 1.0000x reference)
//
#include <hip/hip_runtime.h>
#include <stdint.h>

#define NLEV 16

// Level tables derived exactly from the reference (float32 per_level_scale,
// RES[i] = floor(16 * scale^i), size = min(2^19, (r+1)^3), offsets cumulative;
// total 5,262,476 matches reference N_TOTAL).
__global__ __launch_bounds__(256, 4) void hashgrid_fwd(
    const float* __restrict__ xyz,
    const float2* __restrict__ emb,
    float* __restrict__ out,
    int nb)
{
    constexpr int      kRes[NLEV]  = {16,20,25,32,40,50,64,80,101,128,161,203,256,322,406,512};
    constexpr uint32_t kSize[NLEV] = {4913u,9261u,17576u,35937u,68921u,132651u,274625u,
                                      524288u,524288u,524288u,524288u,524288u,
                                      524288u,524288u,524288u,524288u};
    constexpr uint32_t kOff[NLEV]  = {0u,4913u,14174u,31750u,67687u,136608u,269259u,543884u,
                                      1068172u,1592460u,2116748u,2641036u,3165324u,
                                      3689612u,4213900u,4738188u};

    // Per-wave staging: 64 points x 35 floats = 8960 B; 4 waves/block.
    __shared__ float lds[4 * 64 * 35];

    const int tid  = threadIdx.x;
    const int lane = tid & 63;
    const int wid  = tid >> 6;
    const int p    = blockIdx.x * 256 + tid;
    const int pc   = (p < nb) ? p : (nb - 1);   // clamp; dead waves still compute

    const float x = xyz[3 * pc + 0];
    const float y = xyz[3 * pc + 1];
    const float z = xyz[3 * pc + 2];

    float* wl = &lds[(wid * 64 + lane) * 35];
    wl[0] = x; wl[1] = y; wl[2] = z;

    const float inv = 1.0f / 1.5f;
    const float nx = (x + 0.75f) * inv;
    const float ny = (y + 0.75f) * inv;
    const float nz = (z + 0.75f) * inv;

    #pragma unroll
    for (int l = 0; l < NLEV; ++l) {
        const int      r   = kRes[l];
        const float    rf  = (float)r;
        const uint32_t sz  = kSize[l];
        const uint32_t off = kOff[l];

        const float px = nx * rf, py = ny * rf, pz = nz * rf;
        int bx = (int)floorf(px); bx = bx < 0 ? 0 : (bx > r - 1 ? r - 1 : bx);
        int by = (int)floorf(py); by = by < 0 ? 0 : (by > r - 1 ? r - 1 : by);
        int bz = (int)floorf(pz); bz = bz < 0 ? 0 : (bz > r - 1 ? r - 1 : bz);
        const float fx = px - (float)bx;
        const float fy = py - (float)by;
        const float fz = pz - (float)bz;

        // hash terms: dim0 prime = 1, products fit in 41 bits (int64 semantics ok)
        const uint64_t hx0 = (uint64_t)(uint32_t)bx;
        const uint64_t hx1 = hx0 + 1u;
        const uint64_t hy0 = (uint64_t)(uint32_t)by        * 2654435761ull;
        const uint64_t hy1 = (uint64_t)(uint32_t)(by + 1)  * 2654435761ull;
        const uint64_t hz0 = (uint64_t)(uint32_t)bz        * 805459861ull;
        const uint64_t hz1 = (uint64_t)(uint32_t)(bz + 1)  * 805459861ull;

        const uint64_t yz00 = hy0 ^ hz0;
        const uint64_t yz01 = hy0 ^ hz1;
        const uint64_t yz10 = hy1 ^ hz0;
        const uint64_t yz11 = hy1 ^ hz1;

        // corner order matches CORNERS: (x,y,z) = (i,j,k), i outermost
        const uint32_t i000 = (uint32_t)((hx0 ^ yz00) % sz) + off;
        const uint32_t i001 = (uint32_t)((hx0 ^ yz01) % sz) + off;
        const uint32_t i010 = (uint32_t)((hx0 ^ yz10) % sz) + off;
        const uint32_t i011 = (uint32_t)((hx0 ^ yz11) % sz) + off;
        const uint32_t i100 = (uint32_t)((hx1 ^ yz00) % sz) + off;
        const uint32_t i101 = (uint32_t)((hx1 ^ yz01) % sz) + off;
        const uint32_t i110 = (uint32_t)((hx1 ^ yz10) % sz) + off;
        const uint32_t i111 = (uint32_t)((hx1 ^ yz11) % sz) + off;

        const float2 v000 = emb[i000];
        const float2 v001 = emb[i001];
        const float2 v010 = emb[i010];
        const float2 v011 = emb[i011];
        const float2 v100 = emb[i100];
        const float2 v101 = emb[i101];
        const float2 v110 = emb[i110];
        const float2 v111 = emb[i111];

        const float gx = 1.0f - fx, gy = 1.0f - fy, gz = 1.0f - fz;
        const float w00 = gx * gy;   // x=0,y=0
        const float w01 = gx * fy;   // x=0,y=1
        const float w10 = fx * gy;   // x=1,y=0
        const float w11 = fx * fy;   // x=1,y=1

        float w, f0, f1;
        w = w00 * gz; f0 = w * v000.x;            f1 = w * v000.y;
        w = w00 * fz; f0 = fmaf(w, v001.x, f0);   f1 = fmaf(w, v001.y, f1);
        w = w01 * gz; f0 = fmaf(w, v010.x, f0);   f1 = fmaf(w, v010.y, f1);
        w = w01 * fz; f0 = fmaf(w, v011.x, f0);   f1 = fmaf(w, v011.y, f1);
        w = w10 * gz; f0 = fmaf(w, v100.x, f0);   f1 = fmaf(w, v100.y, f1);
        w = w10 * fz; f0 = fmaf(w, v101.x, f0);   f1 = fmaf(w, v101.y, f1);
        w = w11 * gz; f0 = fmaf(w, v110.x, f0);   f1 = fmaf(w, v110.y, f1);
        w = w11 * fz; f0 = fmaf(w, v111.x, f0);   f1 = fmaf(w, v111.y, f1);

        wl[3 + 2 * l] = f0;
        wl[4 + 2 * l] = f1;
    }

    __syncthreads();

    // Coalesced write of this wave's 64 contiguous points (64*35 floats).
    // nb is a multiple of 64, so waves are fully valid or fully skipped.
    const int wave_gid = blockIdx.x * 4 + wid;
    if (wave_gid * 64 < nb) {
        const float* src = &lds[wid * 64 * 35];
        float* dst = out + (size_t)wave_gid * (64 * 35);
        #pragma unroll
        for (int c = 0; c < 35; ++c)
            dst[c * 64 + lane] = src[c * 64 + lane];
    }
}

extern "C" void kernel_launch(void* const* d_in, const int* in_sizes, int n_in,
                              void* d_out, int out_size, void* d_ws, size_t ws_size,
                              hipStream_t stream) {
    const float*  xyz = (const float*)d_in[0];
    const float2* emb = (const float2*)d_in[1];
    float*        out = (float*)d_out;
    const int nb = in_sizes[0] / 3;           // 1,000,000
    const int blocks = (nb + 255) / 256;      // 3907
    hashgrid_fwd<<<blocks, 256, 0, stream>>>(xyz, emb, out, nb);
}

// Round 2
// 693.873 us; speedup vs baseline: 1.1312x; 1.1312x over previous
//
#include <hip/hip_runtime.h>
#include <stdint.h>
#include <string.h>

#define NLEV 16

// ---------------------------------------------------------------------------
// Shared helpers
// ---------------------------------------------------------------------------
__device__ __forceinline__ void norm_coords(const float* __restrict__ xyz, int p,
                                            float& nx, float& ny, float& nz) {
    const float x = __builtin_nontemporal_load(xyz + 3 * p + 0);
    const float y = __builtin_nontemporal_load(xyz + 3 * p + 1);
    const float z = __builtin_nontemporal_load(xyz + 3 * p + 2);
    const float inv = 1.0f / 1.5f;
    nx = (x + 0.75f) * inv;
    ny = (y + 0.75f) * inv;
    nz = (z + 0.75f) * inv;
}

// ---------------------------------------------------------------------------
// One kernel per big level (levels 7..15): size = 2^19 (pow2 -> 32-bit hash),
// table = 4 MB = exactly one XCD L2. Streaming traffic (xyz in, ws out) is
// nontemporal so it doesn't evict the pinned table.
// ---------------------------------------------------------------------------
template<int R, uint32_t OFF>
__global__ __launch_bounds__(256) void big_level(
    const float* __restrict__ xyz,
    const float2* __restrict__ emb,
    float2* __restrict__ ws,      // level-major slice for this level
    int nb)
{
    const int p = blockIdx.x * 256 + threadIdx.x;
    if (p >= nb) return;

    float nx, ny, nz;
    norm_coords(xyz, p, nx, ny, nz);

    const float rf = (float)R;
    const float px = nx * rf, py = ny * rf, pz = nz * rf;
    int bx = (int)floorf(px); bx = bx < 0 ? 0 : (bx > R - 1 ? R - 1 : bx);
    int by = (int)floorf(py); by = by < 0 ? 0 : (by > R - 1 ? R - 1 : by);
    int bz = (int)floorf(pz); bz = bz < 0 ? 0 : (bz > R - 1 ? R - 1 : bz);
    const float fx = px - (float)bx;
    const float fy = py - (float)by;
    const float fz = pz - (float)bz;

    // pow2 size: only low 19 bits of the XOR matter -> 32-bit math is exact
    const uint32_t M = 524287u;
    const uint32_t hx0 = (uint32_t)bx;
    const uint32_t hx1 = hx0 + 1u;
    const uint32_t hy0 = (uint32_t)by       * 2654435761u;
    const uint32_t hy1 = (uint32_t)(by + 1) * 2654435761u;
    const uint32_t hz0 = (uint32_t)bz       * 805459861u;
    const uint32_t hz1 = (uint32_t)(bz + 1) * 805459861u;

    const uint32_t yz00 = hy0 ^ hz0, yz01 = hy0 ^ hz1;
    const uint32_t yz10 = hy1 ^ hz0, yz11 = hy1 ^ hz1;

    const float2 v000 = emb[((hx0 ^ yz00) & M) + OFF];
    const float2 v001 = emb[((hx0 ^ yz01) & M) + OFF];
    const float2 v010 = emb[((hx0 ^ yz10) & M) + OFF];
    const float2 v011 = emb[((hx0 ^ yz11) & M) + OFF];
    const float2 v100 = emb[((hx1 ^ yz00) & M) + OFF];
    const float2 v101 = emb[((hx1 ^ yz01) & M) + OFF];
    const float2 v110 = emb[((hx1 ^ yz10) & M) + OFF];
    const float2 v111 = emb[((hx1 ^ yz11) & M) + OFF];

    const float gx = 1.0f - fx, gy = 1.0f - fy, gz = 1.0f - fz;
    const float w00 = gx * gy, w01 = gx * fy, w10 = fx * gy, w11 = fx * fy;

    float w, f0, f1;
    w = w00 * gz; f0 = w * v000.x;          f1 = w * v000.y;
    w = w00 * fz; f0 = fmaf(w, v001.x, f0); f1 = fmaf(w, v001.y, f1);
    w = w01 * gz; f0 = fmaf(w, v010.x, f0); f1 = fmaf(w, v010.y, f1);
    w = w01 * fz; f0 = fmaf(w, v011.x, f0); f1 = fmaf(w, v011.y, f1);
    w = w10 * gz; f0 = fmaf(w, v100.x, f0); f1 = fmaf(w, v100.y, f1);
    w = w10 * fz; f0 = fmaf(w, v101.x, f0); f1 = fmaf(w, v101.y, f1);
    w = w11 * gz; f0 = fmaf(w, v110.x, f0); f1 = fmaf(w, v110.y, f1);
    w = w11 * fz; f0 = fmaf(w, v111.x, f0); f1 = fmaf(w, v111.y, f1);

    float2 v = make_float2(f0, f1);
    uint64_t u;
    memcpy(&u, &v, 8);
    __builtin_nontemporal_store(u, (uint64_t*)ws + p);
}

// ---------------------------------------------------------------------------
// Pack kernel: computes small levels 0..6 inline (tables total 2.47 MB,
// L2-resident), merges big-level results from ws, writes out coalesced via
// per-wave LDS transpose (stride 35 is coprime with 32 -> conflict-free).
// ---------------------------------------------------------------------------
__global__ __launch_bounds__(256, 4) void pack_small(
    const float* __restrict__ xyz,
    const float2* __restrict__ emb,
    const float2* __restrict__ ws,
    float* __restrict__ out,
    int nb)
{
    constexpr int      kRes[7]  = {16, 20, 25, 32, 40, 50, 64};
    constexpr uint32_t kSize[7] = {4913u, 9261u, 17576u, 35937u, 68921u, 132651u, 274625u};
    constexpr uint32_t kOff[7]  = {0u, 4913u, 14174u, 31750u, 67687u, 136608u, 269259u};

    __shared__ float lds[4 * 64 * 35];

    const int tid  = threadIdx.x;
    const int lane = tid & 63;
    const int wid  = tid >> 6;
    const int p    = blockIdx.x * 256 + tid;
    const int pc   = (p < nb) ? p : (nb - 1);

    const float x = xyz[3 * pc + 0];
    const float y = xyz[3 * pc + 1];
    const float z = xyz[3 * pc + 2];

    float* wl = &lds[(wid * 64 + lane) * 35];
    wl[0] = x; wl[1] = y; wl[2] = z;

    const float inv = 1.0f / 1.5f;
    const float nx = (x + 0.75f) * inv;
    const float ny = (y + 0.75f) * inv;
    const float nz = (z + 0.75f) * inv;

    #pragma unroll
    for (int l = 0; l < 7; ++l) {
        const int      r   = kRes[l];
        const float    rf  = (float)r;
        const uint32_t sz  = kSize[l];
        const uint32_t off = kOff[l];

        const float px = nx * rf, py = ny * rf, pz = nz * rf;
        int bx = (int)floorf(px); bx = bx < 0 ? 0 : (bx > r - 1 ? r - 1 : bx);
        int by = (int)floorf(py); by = by < 0 ? 0 : (by > r - 1 ? r - 1 : by);
        int bz = (int)floorf(pz); bz = bz < 0 ? 0 : (bz > r - 1 ? r - 1 : bz);
        const float fx = px - (float)bx;
        const float fy = py - (float)by;
        const float fz = pz - (float)bz;

        const uint64_t hx0 = (uint64_t)(uint32_t)bx;
        const uint64_t hx1 = hx0 + 1u;
        const uint64_t hy0 = (uint64_t)(uint32_t)by       * 2654435761ull;
        const uint64_t hy1 = (uint64_t)(uint32_t)(by + 1) * 2654435761ull;
        const uint64_t hz0 = (uint64_t)(uint32_t)bz       * 805459861ull;
        const uint64_t hz1 = (uint64_t)(uint32_t)(bz + 1) * 805459861ull;

        const uint64_t yz00 = hy0 ^ hz0, yz01 = hy0 ^ hz1;
        const uint64_t yz10 = hy1 ^ hz0, yz11 = hy1 ^ hz1;

        const uint32_t i000 = (uint32_t)((hx0 ^ yz00) % sz) + off;
        const uint32_t i001 = (uint32_t)((hx0 ^ yz01) % sz) + off;
        const uint32_t i010 = (uint32_t)((hx0 ^ yz10) % sz) + off;
        const uint32_t i011 = (uint32_t)((hx0 ^ yz11) % sz) + off;
        const uint32_t i100 = (uint32_t)((hx1 ^ yz00) % sz) + off;
        const uint32_t i101 = (uint32_t)((hx1 ^ yz01) % sz) + off;
        const uint32_t i110 = (uint32_t)((hx1 ^ yz10) % sz) + off;
        const uint32_t i111 = (uint32_t)((hx1 ^ yz11) % sz) + off;

        const float2 v000 = emb[i000];
        const float2 v001 = emb[i001];
        const float2 v010 = emb[i010];
        const float2 v011 = emb[i011];
        const float2 v100 = emb[i100];
        const float2 v101 = emb[i101];
        const float2 v110 = emb[i110];
        const float2 v111 = emb[i111];

        const float gx = 1.0f - fx, gy = 1.0f - fy, gz = 1.0f - fz;
        const float w00 = gx * gy, w01 = gx * fy, w10 = fx * gy, w11 = fx * fy;

        float w, f0, f1;
        w = w00 * gz; f0 = w * v000.x;          f1 = w * v000.y;
        w = w00 * fz; f0 = fmaf(w, v001.x, f0); f1 = fmaf(w, v001.y, f1);
        w = w01 * gz; f0 = fmaf(w, v010.x, f0); f1 = fmaf(w, v010.y, f1);
        w = w01 * fz; f0 = fmaf(w, v011.x, f0); f1 = fmaf(w, v011.y, f1);
        w = w10 * gz; f0 = fmaf(w, v100.x, f0); f1 = fmaf(w, v100.y, f1);
        w = w10 * fz; f0 = fmaf(w, v101.x, f0); f1 = fmaf(w, v101.y, f1);
        w = w11 * gz; f0 = fmaf(w, v110.x, f0); f1 = fmaf(w, v110.y, f1);
        w = w11 * fz; f0 = fmaf(w, v111.x, f0); f1 = fmaf(w, v111.y, f1);

        wl[3 + 2 * l] = f0;
        wl[4 + 2 * l] = f1;
    }

    // big-level results from ws (level-major, nontemporal read-once)
    #pragma unroll
    for (int l = 7; l < NLEV; ++l) {
        const uint64_t u = __builtin_nontemporal_load(
            (const uint64_t*)ws + (size_t)(l - 7) * nb + pc);
        float2 v;
        memcpy(&v, &u, 8);
        wl[3 + 2 * l] = v.x;
        wl[4 + 2 * l] = v.y;
    }

    __syncthreads();

    const int wave_gid = blockIdx.x * 4 + wid;
    if (wave_gid * 64 < nb) {
        const float* src = &lds[wid * 64 * 35];
        float* dst = out + (size_t)wave_gid * (64 * 35);
        #pragma unroll
        for (int c = 0; c < 35; ++c)
            dst[c * 64 + lane] = src[c * 64 + lane];
    }
}

// ---------------------------------------------------------------------------
// Fallback: round-1 monolithic kernel (used only if ws_size < 72 MB)
// ---------------------------------------------------------------------------
__global__ __launch_bounds__(256, 4) void hashgrid_mono(
    const float* __restrict__ xyz,
    const float2* __restrict__ emb,
    float* __restrict__ out,
    int nb)
{
    constexpr int      kRes[NLEV]  = {16,20,25,32,40,50,64,80,101,128,161,203,256,322,406,512};
    constexpr uint32_t kSize[NLEV] = {4913u,9261u,17576u,35937u,68921u,132651u,274625u,
                                      524288u,524288u,524288u,524288u,524288u,
                                      524288u,524288u,524288u,524288u};
    constexpr uint32_t kOff[NLEV]  = {0u,4913u,14174u,31750u,67687u,136608u,269259u,543884u,
                                      1068172u,1592460u,2116748u,2641036u,3165324u,
                                      3689612u,4213900u,4738188u};

    __shared__ float lds[4 * 64 * 35];

    const int tid  = threadIdx.x;
    const int lane = tid & 63;
    const int wid  = tid >> 6;
    const int p    = blockIdx.x * 256 + tid;
    const int pc   = (p < nb) ? p : (nb - 1);

    const float x = xyz[3 * pc + 0];
    const float y = xyz[3 * pc + 1];
    const float z = xyz[3 * pc + 2];

    float* wl = &lds[(wid * 64 + lane) * 35];
    wl[0] = x; wl[1] = y; wl[2] = z;

    const float inv = 1.0f / 1.5f;
    const float nx = (x + 0.75f) * inv;
    const float ny = (y + 0.75f) * inv;
    const float nz = (z + 0.75f) * inv;

    #pragma unroll
    for (int l = 0; l < NLEV; ++l) {
        const int      r   = kRes[l];
        const float    rf  = (float)r;
        const uint32_t sz  = kSize[l];
        const uint32_t off = kOff[l];

        const float px = nx * rf, py = ny * rf, pz = nz * rf;
        int bx = (int)floorf(px); bx = bx < 0 ? 0 : (bx > r - 1 ? r - 1 : bx);
        int by = (int)floorf(py); by = by < 0 ? 0 : (by > r - 1 ? r - 1 : by);
        int bz = (int)floorf(pz); bz = bz < 0 ? 0 : (bz > r - 1 ? r - 1 : bz);
        const float fx = px - (float)bx;
        const float fy = py - (float)by;
        const float fz = pz - (float)bz;

        const uint64_t hx0 = (uint64_t)(uint32_t)bx;
        const uint64_t hx1 = hx0 + 1u;
        const uint64_t hy0 = (uint64_t)(uint32_t)by       * 2654435761ull;
        const uint64_t hy1 = (uint64_t)(uint32_t)(by + 1) * 2654435761ull;
        const uint64_t hz0 = (uint64_t)(uint32_t)bz       * 805459861ull;
        const uint64_t hz1 = (uint64_t)(uint32_t)(bz + 1) * 805459861ull;

        const uint64_t yz00 = hy0 ^ hz0, yz01 = hy0 ^ hz1;
        const uint64_t yz10 = hy1 ^ hz0, yz11 = hy1 ^ hz1;

        const uint32_t i000 = (uint32_t)((hx0 ^ yz00) % sz) + off;
        const uint32_t i001 = (uint32_t)((hx0 ^ yz01) % sz) + off;
        const uint32_t i010 = (uint32_t)((hx0 ^ yz10) % sz) + off;
        const uint32_t i011 = (uint32_t)((hx0 ^ yz11) % sz) + off;
        const uint32_t i100 = (uint32_t)((hx1 ^ yz00) % sz) + off;
        const uint32_t i101 = (uint32_t)((hx1 ^ yz01) % sz) + off;
        const uint32_t i110 = (uint32_t)((hx1 ^ yz10) % sz) + off;
        const uint32_t i111 = (uint32_t)((hx1 ^ yz11) % sz) + off;

        const float2 v000 = emb[i000];
        const float2 v001 = emb[i001];
        const float2 v010 = emb[i010];
        const float2 v011 = emb[i011];
        const float2 v100 = emb[i100];
        const float2 v101 = emb[i101];
        const float2 v110 = emb[i110];
        const float2 v111 = emb[i111];

        const float gx = 1.0f - fx, gy = 1.0f - fy, gz = 1.0f - fz;
        const float w00 = gx * gy, w01 = gx * fy, w10 = fx * gy, w11 = fx * fy;

        float w, f0, f1;
        w = w00 * gz; f0 = w * v000.x;          f1 = w * v000.y;
        w = w00 * fz; f0 = fmaf(w, v001.x, f0); f1 = fmaf(w, v001.y, f1);
        w = w01 * gz; f0 = fmaf(w, v010.x, f0); f1 = fmaf(w, v010.y, f1);
        w = w01 * fz; f0 = fmaf(w, v011.x, f0); f1 = fmaf(w, v011.y, f1);
        w = w10 * gz; f0 = fmaf(w, v100.x, f0); f1 = fmaf(w, v100.y, f1);
        w = w10 * fz; f0 = fmaf(w, v101.x, f0); f1 = fmaf(w, v101.y, f1);
        w = w11 * gz; f0 = fmaf(w, v110.x, f0); f1 = fmaf(w, v110.y, f1);
        w = w11 * fz; f0 = fmaf(w, v111.x, f0); f1 = fmaf(w, v111.y, f1);

        wl[3 + 2 * l] = f0;
        wl[4 + 2 * l] = f1;
    }

    __syncthreads();

    const int wave_gid = blockIdx.x * 4 + wid;
    if (wave_gid * 64 < nb) {
        const float* src = &lds[wid * 64 * 35];
        float* dst = out + (size_t)wave_gid * (64 * 35);
        #pragma unroll
        for (int c = 0; c < 35; ++c)
            dst[c * 64 + lane] = src[c * 64 + lane];
    }
}

// ---------------------------------------------------------------------------
extern "C" void kernel_launch(void* const* d_in, const int* in_sizes, int n_in,
                              void* d_out, int out_size, void* d_ws, size_t ws_size,
                              hipStream_t stream) {
    const float*  xyz = (const float*)d_in[0];
    const float2* emb = (const float2*)d_in[1];
    float*        out = (float*)d_out;
    const int nb = in_sizes[0] / 3;           // 1,000,000
    const int blocks = (nb + 255) / 256;      // 3907

    const size_t ws_need = (size_t)9 * (size_t)nb * sizeof(float2);  // 72 MB
    if (ws_size < ws_need) {
        hashgrid_mono<<<blocks, 256, 0, stream>>>(xyz, emb, out, nb);
        return;
    }

    float2* ws = (float2*)d_ws;
    // levels 7..15: R = {80,101,128,161,203,256,322,406,512}
    big_level< 80,  543884u><<<blocks, 256, 0, stream>>>(xyz, emb, ws + (size_t)0 * nb, nb);
    big_level<101, 1068172u><<<blocks, 256, 0, stream>>>(xyz, emb, ws + (size_t)1 * nb, nb);
    big_level<128, 1592460u><<<blocks, 256, 0, stream>>>(xyz, emb, ws + (size_t)2 * nb, nb);
    big_level<161, 2116748u><<<blocks, 256, 0, stream>>>(xyz, emb, ws + (size_t)3 * nb, nb);
    big_level<203, 2641036u><<<blocks, 256, 0, stream>>>(xyz, emb, ws + (size_t)4 * nb, nb);
    big_level<256, 3165324u><<<blocks, 256, 0, stream>>>(xyz, emb, ws + (size_t)5 * nb, nb);
    big_level<322, 3689612u><<<blocks, 256, 0, stream>>>(xyz, emb, ws + (size_t)6 * nb, nb);
    big_level<406, 4213900u><<<blocks, 256, 0, stream>>>(xyz, emb, ws + (size_t)7 * nb, nb);
    big_level<512, 4738188u><<<blocks, 256, 0, stream>>>(xyz, emb, ws + (size_t)8 * nb, nb);
    pack_small<<<blocks, 256, 0, stream>>>(xyz, emb, ws, out, nb);
}